// Round 3
// baseline (249.781 us; speedup 1.0000x reference)
//
#include <hip/hip_runtime.h>
#include <hip/hip_bf16.h>

typedef float f32x4 __attribute__((ext_vector_type(4)));
typedef short s16x8 __attribute__((ext_vector_type(8)));
typedef unsigned short u16x8 __attribute__((ext_vector_type(8)));

#define MFMA16(a,b,c) __builtin_amdgcn_mfma_f32_16x16x32_bf16(a,b,c,0,0,0)

#define NTOK 3136
#define NKV  784
#define NKVP 800
#define CD   256
#define NH   8
#define HD   32
#define PEW  111
#define LOG2E 1.4426950408889634f
#define SC2  (0.17677669529663687f * 1.4426950408889634f)

// manual RNE f32->bf16 (used in prep/epilogues for max precision)
static __device__ __forceinline__ unsigned short f2b(float f){
  unsigned int u = __float_as_uint(f);
  return (unsigned short)((u + 0x7fffu + ((u>>16)&1u)) >> 16);
}
// native cvt for the attention hot loop
static __device__ __forceinline__ unsigned short f2b_fast(float f){
  __hip_bfloat16 h = __float2bfloat16(f);
  return *reinterpret_cast<unsigned short*>(&h);
}

// ---- prep: WqT[c][k], WkvT[c2][k], pwT[c][k] bf16; srwb2[o][khw][ci] reorder
__global__ void k_prepw(const float* __restrict__ Wq, const float* __restrict__ Wkv,
                        const float* __restrict__ pw, const float* __restrict__ srw,
                        unsigned short* __restrict__ WqT, unsigned short* __restrict__ WkvT,
                        unsigned short* __restrict__ pwT, unsigned short* __restrict__ srwb2){
  int i = blockIdx.x*256 + threadIdx.x;             // 524288 total
  if (i < 65536){ int nn=i>>8, kk=i&255; WqT[i] = f2b(Wq[kk*256+nn]); }
  else if (i < 196608){ int j=i-65536; int c2=j>>8, kk=j&255; WkvT[j] = f2b(Wkv[kk*512+c2]); }
  else if (i < 262144){ int j=i-196608; int cc=j>>8, kk=j&255; pwT[j] = f2b(pw[kk*256+cc]); }
  else { int j=i-262144; int o=j>>10, rem=j&1023, khw=rem>>8, ci=rem&255;
         srwb2[j] = f2b(srw[o*1024 + ci*4 + khw]); }
}

// ---- bias2[n][key] = pos[rel]*log2e (f32); pad keys -> -1e5
__global__ void k_bias(const float* __restrict__ pos, float* __restrict__ bias2){
  int key = blockIdx.x*256 + threadIdx.x;
  int n = blockIdx.y;
  if (key >= NKVP) return;
  float v;
  if (key < NKV){
    int nr = (n*9363)>>19, nc = n - nr*56;
    int tt = (key*9363)>>19, mm = key - tt*56;
    v = pos[(tt-nr+55)*PEW + (mm-nc+55)] * LOG2E;
  } else v = -100000.f;
  bias2[(size_t)n*NKVP + key] = v;
}

// ---- zero K pad rows (permuted positions) and V pad cols
__global__ void k_pad(unsigned short* __restrict__ kb, unsigned short* __restrict__ vT){
  int i = blockIdx.x*256 + threadIdx.x;             // 32768
  if (i < 16384){
    int bh=i>>9, r=i&511, ridx=r>>5, d=r&31;
    int row = 776 + (ridx&7) + (ridx>>3)*16;        // rows 776-783, 792-799
    kb[((size_t)bh*NKVP + row)*HD + d] = 0;
  } else {
    int j=i-16384;
    int bh=j>>9, r=j&511, d=r>>4, key=784+(r&15);
    vT[((size_t)bh*HD + d)*NKVP + key] = 0;
  }
}

// ---- transpose+cvt: x (B,C,N) f32 -> xbf (B,N,C) bf16. grid (49,4,4)
__global__ __launch_bounds__(256) void k_xt(const float* __restrict__ x,
                                            unsigned short* __restrict__ xbf){
  __shared__ float tile[64][65];
  const int t = threadIdx.x;
  const int n0 = blockIdx.x*64, c0 = blockIdx.y*64, b = blockIdx.z;
  const int tx = t&15, ty = t>>4;
#pragma unroll
  for (int j=0;j<4;++j){
    f32x4 v = *(const f32x4*)&x[(size_t)(b*CD + c0+ty+j*16)*NTOK + n0 + tx*4];
    tile[ty+j*16][tx*4+0]=v[0]; tile[ty+j*16][tx*4+1]=v[1];
    tile[ty+j*16][tx*4+2]=v[2]; tile[ty+j*16][tx*4+3]=v[3];
  }
  __syncthreads();
  const int nr = t>>2, ccb = (t&3)*16;
  u16x8 o0, o1;
#pragma unroll
  for (int u=0;u<8;++u){ o0[u] = f2b(tile[ccb+u][nr]); o1[u] = f2b(tile[ccb+8+u][nr]); }
  unsigned short* dst = &xbf[((size_t)b*NTOK + n0+nr)*CD + c0 + ccb];
  *(u16x8*)dst = o0;
  *(u16x8*)(dst+8) = o1;
}

// ---- q projection (pre-scaled by scale*log2e). grid (196,4)
__global__ __launch_bounds__(256) void k_qproj(const unsigned short* __restrict__ xbf,
      const unsigned short* __restrict__ WqT, unsigned short* __restrict__ qb){
  const int tid=threadIdx.x, wv=tid>>6, l=tid&63, g=l>>4, ln16=l&15;
  const int bI = blockIdx.x/49;
  const int n0 = (blockIdx.x%49)*64;
  const int m0 = n0 + (wv>>1)*32;
  const int c0 = blockIdx.y*64 + (wv&1)*32;
  f32x4 acc[2][2] = {};
  for (int k0=0; k0<CD; k0+=32){
    s16x8 a[2], bf[2];
#pragma unroll
    for (int mi=0;mi<2;++mi)
      a[mi] = *(const s16x8*)&xbf[((size_t)bI*NTOK + m0+mi*16+ln16)*CD + k0 + g*8];
#pragma unroll
    for (int ni=0;ni<2;++ni)
      bf[ni] = *(const s16x8*)&WqT[(size_t)(c0+ni*16+ln16)*CD + k0 + g*8];
#pragma unroll
    for (int mi=0;mi<2;++mi)
#pragma unroll
      for (int ni=0;ni<2;++ni) acc[mi][ni] = MFMA16(a[mi], bf[ni], acc[mi][ni]);
  }
#pragma unroll
  for (int mi=0;mi<2;++mi)
#pragma unroll
    for (int ni=0;ni<2;++ni){
      int c = c0 + ni*16 + ln16;
#pragma unroll
      for (int r=0;r<4;++r){
        int n = m0 + mi*16 + g*4 + r;
        qb[((size_t)bI*NTOK + n)*CD + c] = f2b(acc[mi][ni][r] * SC2);
      }
    }
}

// ---- conv as GEMM over k'=(khw,ci) with xbf + srwb2. grid (49,4)
__global__ __launch_bounds__(256) void k_conv(const unsigned short* __restrict__ xbf,
      const unsigned short* __restrict__ srwb2, const float* __restrict__ srb,
      float* __restrict__ convo){
  const int tid=threadIdx.x, wv=tid>>6, l=tid&63, g=l>>4, ln16=l&15;
  const int m0 = blockIdx.x*64 + (wv>>1)*32;
  const int c0 = blockIdx.y*64 + (wv&1)*32;
  size_t abase[2][4];
#pragma unroll
  for (int mi=0;mi<2;++mi){
    int m = m0 + mi*16 + ln16;
    int bb = (m>=2352)?3:(m>=1568)?2:(m>=784)?1:0;
    int nk = m - bb*784;
    int pp = (nk*9363)>>18, qq = nk - pp*28;
#pragma unroll
    for (int khw=0;khw<4;++khw){
      int kh = khw>>1, kw = khw&1;
      abase[mi][khw] = ((size_t)bb*NTOK + (2*pp+kh)*56 + 2*qq+kw)*CD;
    }
  }
  f32x4 acc[2][2] = {};
#pragma unroll
  for (int khw=0;khw<4;++khw){
    for (int kc=0; kc<256; kc+=32){
      s16x8 a[2], bf[2];
#pragma unroll
      for (int mi=0;mi<2;++mi)
        a[mi] = *(const s16x8*)&xbf[abase[mi][khw] + kc + g*8];
#pragma unroll
      for (int ni=0;ni<2;++ni)
        bf[ni] = *(const s16x8*)&srwb2[(size_t)(c0+ni*16+ln16)*1024 + khw*256 + kc + g*8];
#pragma unroll
      for (int mi=0;mi<2;++mi)
#pragma unroll
        for (int ni=0;ni<2;++ni) acc[mi][ni] = MFMA16(a[mi], bf[ni], acc[mi][ni]);
    }
  }
#pragma unroll
  for (int mi=0;mi<2;++mi)
#pragma unroll
    for (int ni=0;ni<2;++ni){
      int c = c0 + ni*16 + ln16;
      float bias = srb[c];
#pragma unroll
      for (int r=0;r<4;++r){
        int m = m0 + mi*16 + g*4 + r;
        convo[(size_t)m*CD + c] = acc[mi][ni][r] + bias;
      }
    }
}

// ---- LayerNorm (f32 in, bf16 out). grid 3136, block 256
__global__ void k_ln(const float* __restrict__ co, const float* __restrict__ gam,
                     const float* __restrict__ bet, unsigned short* __restrict__ kvbf){
  const int row = blockIdx.x, t = threadIdx.x;
  float v = co[(size_t)row*CD + t];
  float s = v, s2 = v*v;
#pragma unroll
  for (int o=32; o>0; o>>=1){ s += __shfl_down(s,o); s2 += __shfl_down(s2,o); }
  __shared__ float ps[4], ps2[4];
  int wid = t>>6, lane = t&63;
  if (lane==0){ ps[wid]=s; ps2[wid]=s2; }
  __syncthreads();
  if (t==0){
    float a = ps[0]+ps[1]+ps[2]+ps[3];
    float a2 = ps2[0]+ps2[1]+ps2[2]+ps2[3];
    float mu = a*(1.f/CD);
    float var = a2*(1.f/CD) - mu*mu;
    ps[0] = mu; ps2[0] = rsqrtf(var + 1e-5f);
  }
  __syncthreads();
  float mu = ps[0], rs = ps2[0];
  kvbf[(size_t)row*CD + t] = f2b((v-mu)*rs*gam[t] + bet[t]);
}

// ---- kv projection + scatter: K rows chunk-permuted, V transposed. grid (49,8)
__global__ __launch_bounds__(256) void k_kv(const unsigned short* __restrict__ kvbf,
      const unsigned short* __restrict__ WkvT, unsigned short* __restrict__ kb,
      unsigned short* __restrict__ vT){
  const int tid=threadIdx.x, wv=tid>>6, l=tid&63, g=l>>4, ln16=l&15;
  const int m0 = blockIdx.x*64 + (wv>>1)*32;
  const int c0 = blockIdx.y*64 + (wv&1)*32;
  f32x4 acc[2][2] = {};
  for (int k0=0; k0<CD; k0+=32){
    s16x8 a[2], bf[2];
#pragma unroll
    for (int mi=0;mi<2;++mi)
      a[mi] = *(const s16x8*)&kvbf[(size_t)(m0+mi*16+ln16)*CD + k0 + g*8];
#pragma unroll
    for (int ni=0;ni<2;++ni)
      bf[ni] = *(const s16x8*)&WkvT[(size_t)(c0+ni*16+ln16)*CD + k0 + g*8];
#pragma unroll
    for (int mi=0;mi<2;++mi)
#pragma unroll
      for (int ni=0;ni<2;++ni) acc[mi][ni] = MFMA16(a[mi], bf[ni], acc[mi][ni]);
  }
#pragma unroll
  for (int mi=0;mi<2;++mi)
#pragma unroll
    for (int ni=0;ni<2;++ni){
      int c2 = c0 + ni*16 + ln16;
      int d = c2>>4, hh = (c2>>1)&7;
#pragma unroll
      for (int r=0;r<4;++r){
        int m = m0 + mi*16 + g*4 + r;
        int bq = (m>=2352)?3:(m>=1568)?2:(m>=784)?1:0;
        int nk = m - bq*784;
        unsigned short val = f2b(acc[mi][ni][r]);
        if (c2&1){
          vT[(((size_t)bq*NH+hh)*HD + d)*NKVP + nk] = val;
        } else {
          int chunk = nk & ~31, pos = nk & 31;
          int gg = pos>>3, jj = pos&7;
          int row = (jj<4) ? (gg*4+jj) : (16 + gg*4 + (jj-4));
          kb[(((size_t)bq*NH+hh)*NKVP + chunk + row)*HD + d] = val;
        }
      }
    }
}

// ---- fused MFMA attention, fully in-register softmax. grid (32, 49)
__global__ __launch_bounds__(256) void k_attn(const unsigned short* __restrict__ qb,
      const unsigned short* __restrict__ kb, const unsigned short* __restrict__ vT,
      const float* __restrict__ bias2, unsigned short* __restrict__ aout){
  const int tid=threadIdx.x, wv=tid>>6, l=tid&63, g=l>>4, ln16=l&15;
  const int bh = blockIdx.x, b = bh>>3, h = bh&7;
  const int nw = blockIdx.y*64 + wv*16;
  const s16x8 qf = *(const s16x8*)&qb[((size_t)b*NTOK + nw + ln16)*CD + h*HD + g*8];
  const unsigned short* kptr  = kb + (size_t)bh*NKVP*HD + ln16*HD + g*8;
  const unsigned short* vptr0 = vT + (size_t)bh*HD*NKVP + ln16*NKVP + g*8;
  const unsigned short* vptr1 = vptr0 + 16*NKVP;
  const float* bp = bias2 + (size_t)(nw + ln16)*NKVP + g*8;
  f32x4 accO0 = {}, accO1 = {};
  float S = 0.f;
  const f32x4 zf = {};
#pragma unroll 5
  for (int it=0; it<25; ++it){
    s16x8 ka0 = *(const s16x8*)(kptr);
    s16x8 ka1 = *(const s16x8*)(kptr + 16*HD);
    f32x4 d0 = MFMA16(ka0, qf, zf);
    f32x4 d1 = MFMA16(ka1, qf, zf);
    f32x4 b0 = *(const f32x4*)(bp);
    f32x4 b1 = *(const f32x4*)(bp + 4);
    float p[8];
#pragma unroll
    for (int r=0;r<4;++r){
      p[r]   = exp2f(d0[r] + b0[r]);
      p[4+r] = exp2f(d1[r] + b1[r]);
    }
    S += ((p[0]+p[1])+(p[2]+p[3])) + ((p[4]+p[5])+(p[6]+p[7]));
    s16x8 pf;
#pragma unroll
    for (int j=0;j<8;++j) pf[j] = (short)f2b_fast(p[j]);
    s16x8 v0 = *(const s16x8*)(vptr0);
    s16x8 v1 = *(const s16x8*)(vptr1);
    accO0 = MFMA16(pf, v0, accO0);
    accO1 = MFMA16(pf, v1, accO1);
    kptr += 32*HD; vptr0 += 32; vptr1 += 32; bp += 32;
  }
  S += __shfl_xor(S, 16);
  S += __shfl_xor(S, 32);
#pragma unroll
  for (int r=0;r<4;++r){
    float Sr = __shfl(S, g*4 + r);
    float inv = 1.f / Sr;
    int n = nw + g*4 + r;
    aout[((size_t)b*NTOK + n)*CD + h*HD + ln16]      = f2b(accO0[r]*inv);
    aout[((size_t)b*NTOK + n)*CD + h*HD + 16 + ln16] = f2b(accO1[r]*inv);
  }
}

// ---- out projection: A=pwT rows c, B=aout rows n -> coalesced-in-n stores. grid (196,4)
__global__ __launch_bounds__(256) void k_proj(const unsigned short* __restrict__ ain,
      const unsigned short* __restrict__ pwT, const float* __restrict__ pb,
      float* __restrict__ out){
  const int tid=threadIdx.x, wv=tid>>6, l=tid&63, g=l>>4, ln16=l&15;
  const int bI = blockIdx.x/49;
  const int n0 = (blockIdx.x%49)*64;
  const int nsub = n0 + (wv&1)*32;
  const int c0 = blockIdx.y*64 + (wv>>1)*32;
  f32x4 acc[2][2] = {};   // [mi over c][ni over n]
  for (int k0=0; k0<CD; k0+=32){
    s16x8 a[2], bf[2];
#pragma unroll
    for (int mi=0;mi<2;++mi)
      a[mi] = *(const s16x8*)&pwT[(size_t)(c0+mi*16+ln16)*CD + k0 + g*8];
#pragma unroll
    for (int ni=0;ni<2;++ni)
      bf[ni] = *(const s16x8*)&ain[((size_t)bI*NTOK + nsub+ni*16+ln16)*CD + k0 + g*8];
#pragma unroll
    for (int mi=0;mi<2;++mi)
#pragma unroll
      for (int ni=0;ni<2;++ni) acc[mi][ni] = MFMA16(a[mi], bf[ni], acc[mi][ni]);
  }
#pragma unroll
  for (int mi=0;mi<2;++mi)
#pragma unroll
    for (int r=0;r<4;++r){
      int c = c0 + mi*16 + g*4 + r;
      float bias = pb[c];
#pragma unroll
      for (int ni=0;ni<2;++ni){
        int n = nsub + ni*16 + ln16;
        out[((size_t)bI*CD + c)*NTOK + n] = acc[mi][ni][r] + bias;
      }
    }
}

extern "C" void kernel_launch(void* const* d_in, const int* in_sizes, int n_in,
                              void* d_out, int out_size, void* d_ws, size_t ws_size,
                              hipStream_t stream){
  const float* x   = (const float*)d_in[0];
  const float* Wq  = (const float*)d_in[1];
  const float* Wkv = (const float*)d_in[2];
  const float* srw = (const float*)d_in[3];
  const float* srb = (const float*)d_in[4];
  const float* lng = (const float*)d_in[5];
  const float* lnb = (const float*)d_in[6];
  const float* pos = (const float*)d_in[7];
  const float* pw  = (const float*)d_in[8];
  const float* pb  = (const float*)d_in[9];
  float* out = (float*)d_out;

  unsigned char* p = (unsigned char*)d_ws;
  unsigned short* WqT   = (unsigned short*)(p + 0);         // 131072 B
  unsigned short* WkvT  = (unsigned short*)(p + 131072);    // 262144 B
  unsigned short* pwT   = (unsigned short*)(p + 393216);    // 131072 B
  unsigned short* srwb2 = (unsigned short*)(p + 524288);    // 524288 B
  float*          bias2 = (float*)        (p + 1048576);    // 10035200 B
  unsigned short* xbf   = (unsigned short*)(p + 11083776);  // 6422528 B
  unsigned short* qbuf  = (unsigned short*)(p + 17506304);  // 6422528 B
  float*          convo = (float*)        (p + 23928832);   // 3211264 B
  unsigned short* kvbf  = (unsigned short*)(p + 27140096);  // 1605632 B
  unsigned short* kbuf  = (unsigned short*)(p + 28745728);  // 1638400 B
  unsigned short* vT    = (unsigned short*)(p + 30384128);  // 1638400 B
  unsigned short* aout  = (unsigned short*)(p + 32022528);  // 6422528 B

  k_prepw<<<2048, 256, 0, stream>>>(Wq, Wkv, pw, srw, WqT, WkvT, pwT, srwb2);
  k_bias <<<dim3(4,3136), 256, 0, stream>>>(pos, bias2);
  k_pad  <<<128, 256, 0, stream>>>(kbuf, vT);
  k_xt   <<<dim3(49,4,4), 256, 0, stream>>>(x, xbf);
  k_qproj<<<dim3(196,4), 256, 0, stream>>>(xbf, WqT, qbuf);
  k_conv <<<dim3(49,4),  256, 0, stream>>>(xbf, srwb2, srb, convo);
  k_ln   <<<3136, 256, 0, stream>>>(convo, lng, lnb, kvbf);
  k_kv   <<<dim3(49,8),  256, 0, stream>>>(kvbf, WkvT, kbuf, vT);
  k_attn <<<dim3(32,49), 256, 0, stream>>>(qbuf, kbuf, vT, bias2, aout);
  k_proj <<<dim3(196,4), 256, 0, stream>>>(aout, pwT, pb, out);
}

// Round 6
// 220.134 us; speedup vs baseline: 1.1347x; 1.1347x over previous
//
#include <hip/hip_runtime.h>
#include <hip/hip_bf16.h>

typedef float f32x4 __attribute__((ext_vector_type(4)));
typedef short s16x8 __attribute__((ext_vector_type(8)));
typedef unsigned short u16x8 __attribute__((ext_vector_type(8)));

#define MFMA16(a,b,c) __builtin_amdgcn_mfma_f32_16x16x32_bf16(a,b,c,0,0,0)

#define NTOK 3136
#define NKV  784
#define NKVP 800
#define CD   256
#define NH   8
#define HD   32
#define PEW  111
#define LOG2E 1.4426950408889634f
#define SC2  (0.17677669529663687f * 1.4426950408889634f)

static __device__ __forceinline__ unsigned short f2b(float f){
  unsigned int u = __float_as_uint(f);
  return (unsigned short)((u + 0x7fffu + ((u>>16)&1u)) >> 16);
}
static __device__ __forceinline__ unsigned short f2b_fast(float f){
  __hip_bfloat16 h = __float2bfloat16(f);
  return *reinterpret_cast<unsigned short*>(&h);
}
static __device__ __forceinline__ float b2f(unsigned short u){
  return __uint_as_float(((unsigned int)u)<<16);
}

// ---- prep: WqT[c][k], WkvT[c2][k], pwT[c][k] bf16; srwb2[o][khw][ci]
__global__ void k_prepw(const float* __restrict__ Wq, const float* __restrict__ Wkv,
                        const float* __restrict__ pw, const float* __restrict__ srw,
                        unsigned short* __restrict__ WqT, unsigned short* __restrict__ WkvT,
                        unsigned short* __restrict__ pwT, unsigned short* __restrict__ srwb2){
  int i = blockIdx.x*256 + threadIdx.x;             // 524288 total
  if (i < 65536){ int nn=i>>8, kk=i&255; WqT[i] = f2b(Wq[kk*256+nn]); }
  else if (i < 196608){ int j=i-65536; int c2=j>>8, kk=j&255; WkvT[j] = f2b(Wkv[kk*512+c2]); }
  else if (i < 262144){ int j=i-196608; int cc=j>>8, kk=j&255; pwT[j] = f2b(pw[kk*256+cc]); }
  else { int j=i-262144; int o=j>>10, rem=j&1023, khw=rem>>8, ci=rem&255;
         srwb2[j] = f2b(srw[o*1024 + ci*4 + khw]); }
}

// ---- bias2[n][key] = pos[rel]*log2e (bf16); pad keys -> -1e5
__global__ void k_bias(const float* __restrict__ pos, unsigned short* __restrict__ bias2){
  int key = blockIdx.x*256 + threadIdx.x;
  int n = blockIdx.y;
  if (key >= NKVP) return;
  float v;
  if (key < NKV){
    int nr = (n*9363)>>19, nc = n - nr*56;
    int tt = (key*9363)>>19, mm = key - tt*56;
    v = pos[(tt-nr+55)*PEW + (mm-nc+55)] * LOG2E;
  } else v = -100000.f;
  bias2[(size_t)n*NKVP + key] = f2b(v);
}

// ---- zero K pad rows (permuted positions) and V pad cols
__global__ void k_pad(unsigned short* __restrict__ kb, unsigned short* __restrict__ vT){
  int i = blockIdx.x*256 + threadIdx.x;             // 32768
  if (i < 16384){
    int bh=i>>9, r=i&511, ridx=r>>5, d=r&31;
    int row = 776 + (ridx&7) + (ridx>>3)*16;        // rows 776-783, 792-799
    kb[((size_t)bh*NKVP + row)*HD + d] = 0;
  } else {
    int j=i-16384;
    int bh=j>>9, r=j&511, d=r>>4, key=784+(r&15);
    vT[((size_t)bh*HD + d)*NKVP + key] = 0;
  }
}

// ---- transpose+cvt: x (B,C,N) f32 -> xbf (B,N,C) bf16. grid (49,4,4)
__global__ __launch_bounds__(256) void k_xt(const float* __restrict__ x,
                                            unsigned short* __restrict__ xbf){
  __shared__ float tile[64][65];
  const int t = threadIdx.x;
  const int n0 = blockIdx.x*64, c0 = blockIdx.y*64, b = blockIdx.z;
  const int tx = t&15, ty = t>>4;
#pragma unroll
  for (int j=0;j<4;++j){
    f32x4 v = *(const f32x4*)&x[(size_t)(b*CD + c0+ty+j*16)*NTOK + n0 + tx*4];
    tile[ty+j*16][tx*4+0]=v[0]; tile[ty+j*16][tx*4+1]=v[1];
    tile[ty+j*16][tx*4+2]=v[2]; tile[ty+j*16][tx*4+3]=v[3];
  }
  __syncthreads();
  const int nr = t>>2, ccb = (t&3)*16;
  u16x8 o0, o1;
#pragma unroll
  for (int u=0;u<8;++u){ o0[u] = f2b(tile[ccb+u][nr]); o1[u] = f2b(tile[ccb+8+u][nr]); }
  unsigned short* dst = &xbf[((size_t)b*NTOK + n0+nr)*CD + c0 + ccb];
  *(u16x8*)dst = o0;
  *(u16x8*)(dst+8) = o1;
}

// ---- q projection (pre-scaled by scale*log2e), pipelined. grid (196,4)
__global__ __launch_bounds__(256) void k_qproj(const unsigned short* __restrict__ xbf,
      const unsigned short* __restrict__ WqT, unsigned short* __restrict__ qb){
  const int tid=threadIdx.x, wv=tid>>6, l=tid&63, g=l>>4, ln16=l&15;
  const int bI = blockIdx.x/49;
  const int n0 = (blockIdx.x%49)*64;
  const int m0 = n0 + (wv>>1)*32;
  const int c0 = blockIdx.y*64 + (wv&1)*32;
  const unsigned short* ap0 = &xbf[((size_t)bI*NTOK + m0+ln16)*CD + g*8];
  const unsigned short* ap1 = ap0 + 16*CD;
  const unsigned short* bp0 = &WqT[(size_t)(c0+ln16)*CD + g*8];
  const unsigned short* bp1 = bp0 + 16*CD;
  f32x4 acc[2][2] = {};
  s16x8 a0 = *(const s16x8*)ap0, a1 = *(const s16x8*)ap1;
  s16x8 w0 = *(const s16x8*)bp0, w1 = *(const s16x8*)bp1;
#pragma unroll
  for (int k0=0; k0<CD; k0+=32){
    s16x8 na0 = *(const s16x8*)(ap0 + k0+32);
    s16x8 na1 = *(const s16x8*)(ap1 + k0+32);
    s16x8 nw0 = *(const s16x8*)(bp0 + k0+32);
    s16x8 nw1 = *(const s16x8*)(bp1 + k0+32);
    acc[0][0] = MFMA16(a0, w0, acc[0][0]);
    acc[0][1] = MFMA16(a0, w1, acc[0][1]);
    acc[1][0] = MFMA16(a1, w0, acc[1][0]);
    acc[1][1] = MFMA16(a1, w1, acc[1][1]);
    a0=na0; a1=na1; w0=nw0; w1=nw1;
  }
#pragma unroll
  for (int mi=0;mi<2;++mi)
#pragma unroll
    for (int ni=0;ni<2;++ni){
      int c = c0 + ni*16 + ln16;
#pragma unroll
      for (int r=0;r<4;++r){
        int n = m0 + mi*16 + g*4 + r;
        qb[((size_t)bI*NTOK + n)*CD + c] = f2b(acc[mi][ni][r] * SC2);
      }
    }
}

// ---- conv as GEMM over k'=(khw,ci), pipelined, fully unrolled. grid (49,4)
__global__ __launch_bounds__(256) void k_conv(const unsigned short* __restrict__ xbf,
      const unsigned short* __restrict__ srwb2, const float* __restrict__ srb,
      float* __restrict__ convo){
  const int tid=threadIdx.x, wv=tid>>6, l=tid&63, g=l>>4, ln16=l&15;
  const int m0 = blockIdx.x*64 + (wv>>1)*32;
  const int c0 = blockIdx.y*64 + (wv&1)*32;
  size_t abase[2][4];
#pragma unroll
  for (int mi=0;mi<2;++mi){
    int m = m0 + mi*16 + ln16;
    int bb = (m>=2352)?3:(m>=1568)?2:(m>=784)?1:0;
    int nk = m - bb*784;
    int pp = (nk*9363)>>18, qq = nk - pp*28;
#pragma unroll
    for (int khw=0;khw<4;++khw){
      int kh = khw>>1, kw = khw&1;
      abase[mi][khw] = ((size_t)bb*NTOK + (2*pp+kh)*56 + 2*qq+kw)*CD;
    }
  }
  const unsigned short* wp0 = &srwb2[(size_t)(c0+ln16)*1024 + g*8];
  const unsigned short* wp1 = wp0 + 16*1024;
  f32x4 acc[2][2] = {};
  s16x8 a0 = *(const s16x8*)&xbf[abase[0][0] + g*8];
  s16x8 a1 = *(const s16x8*)&xbf[abase[1][0] + g*8];
  s16x8 w0 = *(const s16x8*)wp0;
  s16x8 w1 = *(const s16x8*)wp1;
#pragma unroll
  for (int s=0; s<32; ++s){
    const int s1 = s+1;
    const int khw2 = (s1>>3)&3, kc2 = (s1&7)*32;
    const int woff = (s1&31)*32;
    s16x8 na0 = *(const s16x8*)&xbf[abase[0][khw2] + kc2 + g*8];
    s16x8 na1 = *(const s16x8*)&xbf[abase[1][khw2] + kc2 + g*8];
    s16x8 nw0 = *(const s16x8*)(wp0 + woff);
    s16x8 nw1 = *(const s16x8*)(wp1 + woff);
    acc[0][0] = MFMA16(a0, w0, acc[0][0]);
    acc[0][1] = MFMA16(a0, w1, acc[0][1]);
    acc[1][0] = MFMA16(a1, w0, acc[1][0]);
    acc[1][1] = MFMA16(a1, w1, acc[1][1]);
    a0=na0; a1=na1; w0=nw0; w1=nw1;
  }
#pragma unroll
  for (int mi=0;mi<2;++mi)
#pragma unroll
    for (int ni=0;ni<2;++ni){
      int c = c0 + ni*16 + ln16;
      float bias = srb[c];
#pragma unroll
      for (int r=0;r<4;++r){
        int m = m0 + mi*16 + g*4 + r;
        convo[(size_t)m*CD + c] = acc[mi][ni][r] + bias;
      }
    }
}

// ---- LayerNorm (f32 in, bf16 out). grid 3136, block 256
__global__ void k_ln(const float* __restrict__ co, const float* __restrict__ gam,
                     const float* __restrict__ bet, unsigned short* __restrict__ kvbf){
  const int row = blockIdx.x, t = threadIdx.x;
  float v = co[(size_t)row*CD + t];
  float s = v, s2 = v*v;
#pragma unroll
  for (int o=32; o>0; o>>=1){ s += __shfl_down(s,o); s2 += __shfl_down(s2,o); }
  __shared__ float ps[4], ps2[4];
  int wid = t>>6, lane = t&63;
  if (lane==0){ ps[wid]=s; ps2[wid]=s2; }
  __syncthreads();
  if (t==0){
    float a = ps[0]+ps[1]+ps[2]+ps[3];
    float a2 = ps2[0]+ps2[1]+ps2[2]+ps2[3];
    float mu = a*(1.f/CD);
    float var = a2*(1.f/CD) - mu*mu;
    ps[0] = mu; ps2[0] = rsqrtf(var + 1e-5f);
  }
  __syncthreads();
  float mu = ps[0], rs = ps2[0];
  kvbf[(size_t)row*CD + t] = f2b((v-mu)*rs*gam[t] + bet[t]);
}

// ---- kv projection + scatter: K rows chunk-permuted, V transposed. grid (49,8)
__global__ __launch_bounds__(256) void k_kv(const unsigned short* __restrict__ kvbf,
      const unsigned short* __restrict__ WkvT, unsigned short* __restrict__ kb,
      unsigned short* __restrict__ vT){
  const int tid=threadIdx.x, wv=tid>>6, l=tid&63, g=l>>4, ln16=l&15;
  const int m0 = blockIdx.x*64 + (wv>>1)*32;
  const int c0 = blockIdx.y*64 + (wv&1)*32;
  const unsigned short* ap0 = &kvbf[(size_t)(m0+ln16)*CD + g*8];
  const unsigned short* ap1 = ap0 + 16*CD;
  const unsigned short* bp0 = &WkvT[(size_t)(c0+ln16)*CD + g*8];
  const unsigned short* bp1 = bp0 + 16*CD;
  f32x4 acc[2][2] = {};
  s16x8 a0 = *(const s16x8*)ap0, a1 = *(const s16x8*)ap1;
  s16x8 w0 = *(const s16x8*)bp0, w1 = *(const s16x8*)bp1;
#pragma unroll
  for (int k0=0; k0<CD; k0+=32){
    s16x8 na0 = *(const s16x8*)(ap0 + k0+32);
    s16x8 na1 = *(const s16x8*)(ap1 + k0+32);
    s16x8 nw0 = *(const s16x8*)(bp0 + k0+32);
    s16x8 nw1 = *(const s16x8*)(bp1 + k0+32);
    acc[0][0] = MFMA16(a0, w0, acc[0][0]);
    acc[0][1] = MFMA16(a0, w1, acc[0][1]);
    acc[1][0] = MFMA16(a1, w0, acc[1][0]);
    acc[1][1] = MFMA16(a1, w1, acc[1][1]);
    a0=na0; a1=na1; w0=nw0; w1=nw1;
  }
#pragma unroll
  for (int mi=0;mi<2;++mi)
#pragma unroll
    for (int ni=0;ni<2;++ni){
      int c2 = c0 + ni*16 + ln16;
      int d = c2>>4, hh = (c2>>1)&7;
#pragma unroll
      for (int r=0;r<4;++r){
        int m = m0 + mi*16 + g*4 + r;
        int bq = (m>=2352)?3:(m>=1568)?2:(m>=784)?1:0;
        int nk = m - bq*784;
        unsigned short val = f2b(acc[mi][ni][r]);
        if (c2&1){
          vT[(((size_t)bq*NH+hh)*HD + d)*NKVP + nk] = val;
        } else {
          int chunk = nk & ~31, pos = nk & 31;
          int gg = pos>>3, jj = pos&7;
          int row = (jj<4) ? (gg*4+jj) : (16 + gg*4 + (jj-4));
          kb[(((size_t)bq*NH+hh)*NKVP + chunk + row)*HD + d] = val;
        }
      }
    }
}

// ---- fused MFMA attention, register-pipelined. grid (49, 32) = (ntile, bh)
__global__ __launch_bounds__(256) void k_attn(const unsigned short* __restrict__ qb,
      const unsigned short* __restrict__ kb, const unsigned short* __restrict__ vT,
      const unsigned short* __restrict__ bias2, unsigned short* __restrict__ aout){
  const int tid=threadIdx.x, wv=tid>>6, l=tid&63, g=l>>4, ln16=l&15;
  const int bh = blockIdx.y, b = bh>>3, h = bh&7;
  const int nw = blockIdx.x*64 + wv*16;
  const s16x8 qf = *(const s16x8*)&qb[((size_t)b*NTOK + nw + ln16)*CD + h*HD + g*8];
  const unsigned short* kptr  = kb + (size_t)bh*NKVP*HD + ln16*HD + g*8;
  const unsigned short* vptr0 = vT + (size_t)bh*HD*NKVP + ln16*NKVP + g*8;
  const unsigned short* vptr1 = vptr0 + 16*NKVP;
  const unsigned short* bp = bias2 + (size_t)(nw + ln16)*NKVP + g*8;
  f32x4 accO0 = {}, accO1 = {};
  float S = 0.f;
  const f32x4 zf = {};
  s16x8 ka0 = *(const s16x8*)(kptr);
  s16x8 ka1 = *(const s16x8*)(kptr + 16*HD);
  s16x8 v0  = *(const s16x8*)(vptr0);
  s16x8 v1  = *(const s16x8*)(vptr1);
  u16x8 bb  = *(const u16x8*)(bp);
#pragma unroll 5
  for (int it=0; it<25; ++it){
    kptr += 32*HD; vptr0 += 32; vptr1 += 32; bp += 32;
    s16x8 nk0 = *(const s16x8*)(kptr);
    s16x8 nk1 = *(const s16x8*)(kptr + 16*HD);
    s16x8 nv0 = *(const s16x8*)(vptr0);
    s16x8 nv1 = *(const s16x8*)(vptr1);
    u16x8 nbb = *(const u16x8*)(bp);
    f32x4 d0 = MFMA16(ka0, qf, zf);
    f32x4 d1 = MFMA16(ka1, qf, zf);
    float p[8];
#pragma unroll
    for (int r=0;r<4;++r){
      p[r]   = exp2f(d0[r] + b2f(bb[r]));
      p[4+r] = exp2f(d1[r] + b2f(bb[4+r]));
    }
    S += ((p[0]+p[1])+(p[2]+p[3])) + ((p[4]+p[5])+(p[6]+p[7]));
    s16x8 pf;
#pragma unroll
    for (int j=0;j<8;++j) pf[j] = (short)f2b_fast(p[j]);
    accO0 = MFMA16(pf, v0, accO0);
    accO1 = MFMA16(pf, v1, accO1);
    ka0=nk0; ka1=nk1; v0=nv0; v1=nv1; bb=nbb;
  }
  S += __shfl_xor(S, 16);
  S += __shfl_xor(S, 32);
#pragma unroll
  for (int r=0;r<4;++r){
    float Sr = __shfl(S, g*4 + r);
    float inv = 1.f / Sr;
    int n = nw + g*4 + r;
    aout[((size_t)b*NTOK + n)*CD + h*HD + ln16]      = f2b(accO0[r]*inv);
    aout[((size_t)b*NTOK + n)*CD + h*HD + 16 + ln16] = f2b(accO1[r]*inv);
  }
}

// ---- out projection: A=pwT rows c, B=aout rows n, pipelined. grid (196,4)
__global__ __launch_bounds__(256) void k_proj(const unsigned short* __restrict__ ain,
      const unsigned short* __restrict__ pwT, const float* __restrict__ pb,
      float* __restrict__ out){
  const int tid=threadIdx.x, wv=tid>>6, l=tid&63, g=l>>4, ln16=l&15;
  const int bI = blockIdx.x/49;
  const int n0 = (blockIdx.x%49)*64;
  const int nsub = n0 + (wv&1)*32;
  const int c0 = blockIdx.y*64 + (wv>>1)*32;
  const unsigned short* ap0 = &pwT[(size_t)(c0+ln16)*CD + g*8];
  const unsigned short* ap1 = ap0 + 16*CD;
  const unsigned short* bp0 = &ain[((size_t)bI*NTOK + nsub+ln16)*CD + g*8];
  const unsigned short* bp1 = bp0 + 16*CD;
  f32x4 acc[2][2] = {};   // [mi over c][ni over n]
  s16x8 a0 = *(const s16x8*)ap0, a1 = *(const s16x8*)ap1;
  s16x8 w0 = *(const s16x8*)bp0, w1 = *(const s16x8*)bp1;
#pragma unroll
  for (int k0=0; k0<CD; k0+=32){
    s16x8 na0 = *(const s16x8*)(ap0 + k0+32);
    s16x8 na1 = *(const s16x8*)(ap1 + k0+32);
    s16x8 nw0 = *(const s16x8*)(bp0 + k0+32);
    s16x8 nw1 = *(const s16x8*)(bp1 + k0+32);
    acc[0][0] = MFMA16(a0, w0, acc[0][0]);
    acc[0][1] = MFMA16(a0, w1, acc[0][1]);
    acc[1][0] = MFMA16(a1, w0, acc[1][0]);
    acc[1][1] = MFMA16(a1, w1, acc[1][1]);
    a0=na0; a1=na1; w0=nw0; w1=nw1;
  }
#pragma unroll
  for (int mi=0;mi<2;++mi)
#pragma unroll
    for (int r=0;r<4;++r){
      int c = c0 + mi*16 + g*4 + r;
      float bias = pb[c];
#pragma unroll
      for (int ni=0;ni<2;++ni){
        int n = nsub + ni*16 + ln16;
        out[((size_t)bI*CD + c)*NTOK + n] = acc[mi][ni][r] + bias;
      }
    }
}

extern "C" void kernel_launch(void* const* d_in, const int* in_sizes, int n_in,
                              void* d_out, int out_size, void* d_ws, size_t ws_size,
                              hipStream_t stream){
  const float* x   = (const float*)d_in[0];
  const float* Wq  = (const float*)d_in[1];
  const float* Wkv = (const float*)d_in[2];
  const float* srw = (const float*)d_in[3];
  const float* srb = (const float*)d_in[4];
  const float* lng = (const float*)d_in[5];
  const float* lnb = (const float*)d_in[6];
  const float* pos = (const float*)d_in[7];
  const float* pw  = (const float*)d_in[8];
  const float* pb  = (const float*)d_in[9];
  float* out = (float*)d_out;

  unsigned char* p = (unsigned char*)d_ws;
  unsigned short* WqT   = (unsigned short*)(p + 0);         // 131072 B
  unsigned short* WkvT  = (unsigned short*)(p + 131072);    // 262144 B
  unsigned short* pwT   = (unsigned short*)(p + 393216);    // 131072 B
  unsigned short* srwb2 = (unsigned short*)(p + 524288);    // 524288 B
  unsigned short* bias2 = (unsigned short*)(p + 1048576);   // 5017600 B (bf16)
  unsigned short* xbf   = (unsigned short*)(p + 6066176);   // 6422528 B
  unsigned short* qbuf  = (unsigned short*)(p + 12488704);  // 6422528 B
  float*          convo = (float*)        (p + 18911232);   // 3211264 B
  unsigned short* kvbf  = (unsigned short*)(p + 22122496);  // 1605632 B
  unsigned short* kbuf  = (unsigned short*)(p + 23728128);  // 1638400 B
  unsigned short* vT    = (unsigned short*)(p + 25366528);  // 1638400 B
  unsigned short* aout  = (unsigned short*)(p + 27004928);  // 6422528 B
  // tail pad: 64 KiB after aout (prefetch over-reads land here)      -> total 33492992

  k_prepw<<<2048, 256, 0, stream>>>(Wq, Wkv, pw, srw, WqT, WkvT, pwT, srwb2);
  k_bias <<<dim3(4,3136), 256, 0, stream>>>(pos, bias2);
  k_pad  <<<128, 256, 0, stream>>>(kbuf, vT);
  k_xt   <<<dim3(49,4,4), 256, 0, stream>>>(x, xbf);
  k_qproj<<<dim3(196,4), 256, 0, stream>>>(xbf, WqT, qbuf);
  k_conv <<<dim3(49,4),  256, 0, stream>>>(xbf, srwb2, srb, convo);
  k_ln   <<<3136, 256, 0, stream>>>(convo, lng, lnb, kvbf);
  k_kv   <<<dim3(49,8),  256, 0, stream>>>(kvbf, WkvT, kbuf, vT);
  k_attn <<<dim3(49,32), 256, 0, stream>>>(qbuf, kbuf, vT, bias2, aout);
  k_proj <<<dim3(196,4), 256, 0, stream>>>(aout, pwT, pb, out);
}

// Round 7
// 198.152 us; speedup vs baseline: 1.2606x; 1.1109x over previous
//
#include <hip/hip_runtime.h>
#include <hip/hip_bf16.h>

typedef float f32x4 __attribute__((ext_vector_type(4)));
typedef short s16x8 __attribute__((ext_vector_type(8)));
typedef unsigned short u16x4 __attribute__((ext_vector_type(4)));
typedef unsigned short u16x8 __attribute__((ext_vector_type(8)));

#define MFMA16(a,b,c) __builtin_amdgcn_mfma_f32_16x16x32_bf16(a,b,c,0,0,0)

#define NTOK 3136
#define NKV  784
#define NKVP 800
#define CD   256
#define NH   8
#define HD   32
#define PEW  111
#define LOG2E 1.4426950408889634f
#define SC2  (0.17677669529663687f * 1.4426950408889634f)

static __device__ __forceinline__ unsigned short f2b(float f){
  unsigned int u = __float_as_uint(f);
  return (unsigned short)((u + 0x7fffu + ((u>>16)&1u)) >> 16);
}
static __device__ __forceinline__ unsigned short f2b_fast(float f){
  __hip_bfloat16 h = __float2bfloat16(f);
  return *reinterpret_cast<unsigned short*>(&h);
}
static __device__ __forceinline__ float b2f(unsigned short u){
  return __uint_as_float(((unsigned int)u)<<16);
}
static __device__ __forceinline__ void gload16(const unsigned short* g, unsigned short* l){
  __builtin_amdgcn_global_load_lds(
      (const __attribute__((address_space(1))) unsigned int*)g,
      (__attribute__((address_space(3))) unsigned int*)l, 16, 0, 0);
}

// ---- fused prep: [0,2048) prepw | [2048,2176) pad | [2176,5312) bias | [5312,6096) xt
__global__ __launch_bounds__(256) void k_prep(
      const float* __restrict__ Wq, const float* __restrict__ Wkv,
      const float* __restrict__ pw, const float* __restrict__ srw,
      const float* __restrict__ pos, const float* __restrict__ x,
      unsigned short* __restrict__ WqT, unsigned short* __restrict__ WkvT,
      unsigned short* __restrict__ pwT, unsigned short* __restrict__ srwb2,
      unsigned short* __restrict__ bias2, unsigned short* __restrict__ xbf,
      unsigned short* __restrict__ kb, unsigned short* __restrict__ vT){
  __shared__ float tile[64][65];
  const int blk = blockIdx.x, t = threadIdx.x;
  if (blk < 2048){
    int i = blk*256 + t;
    if (i < 65536){ int nn=i>>8, kk=i&255; WqT[i] = f2b(Wq[kk*256+nn]); }
    else if (i < 196608){ int j=i-65536; int c2=j>>8, kk=j&255; WkvT[j] = f2b(Wkv[kk*512+c2]); }
    else if (i < 262144){ int j=i-196608; int cc=j>>8, kk=j&255; pwT[j] = f2b(pw[kk*256+cc]); }
    else { int j=i-262144; int o=j>>10, rem=j&1023, khw=rem>>8, ci=rem&255;
           srwb2[j] = f2b(srw[o*1024 + ci*4 + khw]); }
  } else if (blk < 2176){
    int i = (blk-2048)*256 + t;                 // 32768
    if (i < 16384){
      int bh=i>>9, r=i&511, ridx=r>>5, d=r&31;
      int row = 776 + (ridx&7) + (ridx>>3)*16;  // permuted pad rows
      kb[((size_t)bh*NKVP + row)*HD + d] = 0;
    } else {
      int j=i-16384;
      int bh=j>>9, r=j&511, d=r>>4, key=784+(r&15);
      vT[((size_t)bh*HD + d)*NKVP + key] = 0;
    }
  } else if (blk < 5312){
    int n = blk - 2176;
    if (t < 200){
      int nr = (n*9363)>>19, nc = n - nr*56;
      u16x4 o;
#pragma unroll
      for (int j=0;j<4;++j){
        int key = t*4 + j;
        float v;
        if (key < NKV){
          int tt = (key*9363)>>19, mm = key - tt*56;
          v = pos[(tt-nr+55)*PEW + (mm-nc+55)] * LOG2E;
        } else v = -100000.f;
        o[j] = f2b(v);
      }
      *(u16x4*)&bias2[(size_t)n*NKVP + t*4] = o;
    }
  } else {
    int bx = blk - 5312;
    const int n0 = (bx%49)*64; int c4 = bx/49;
    const int c0 = (c4&3)*64, b = c4>>2;
    const int tx = t&15, ty = t>>4;
#pragma unroll
    for (int j=0;j<4;++j){
      f32x4 v = *(const f32x4*)&x[(size_t)(b*CD + c0+ty+j*16)*NTOK + n0 + tx*4];
      tile[ty+j*16][tx*4+0]=v[0]; tile[ty+j*16][tx*4+1]=v[1];
      tile[ty+j*16][tx*4+2]=v[2]; tile[ty+j*16][tx*4+3]=v[3];
    }
    __syncthreads();
    const int nr = t>>2, ccb = (t&3)*16;
    u16x8 o0, o1;
#pragma unroll
    for (int u=0;u<8;++u){ o0[u] = f2b(tile[ccb+u][nr]); o1[u] = f2b(tile[ccb+8+u][nr]); }
    unsigned short* dst = &xbf[((size_t)b*NTOK + n0+nr)*CD + c0 + ccb];
    *(u16x8*)dst = o0;
    *(u16x8*)(dst+8) = o1;
  }
}

// ---- q projection (pre-scaled by scale*log2e), pipelined. grid (196,4)
__global__ __launch_bounds__(256) void k_qproj(const unsigned short* __restrict__ xbf,
      const unsigned short* __restrict__ WqT, unsigned short* __restrict__ qb){
  const int tid=threadIdx.x, wv=tid>>6, l=tid&63, g=l>>4, ln16=l&15;
  const int bI = blockIdx.x/49;
  const int n0 = (blockIdx.x%49)*64;
  const int m0 = n0 + (wv>>1)*32;
  const int c0 = blockIdx.y*64 + (wv&1)*32;
  const unsigned short* ap0 = &xbf[((size_t)bI*NTOK + m0+ln16)*CD + g*8];
  const unsigned short* ap1 = ap0 + 16*CD;
  const unsigned short* bp0 = &WqT[(size_t)(c0+ln16)*CD + g*8];
  const unsigned short* bp1 = bp0 + 16*CD;
  f32x4 acc[2][2] = {};
  s16x8 a0 = *(const s16x8*)ap0, a1 = *(const s16x8*)ap1;
  s16x8 w0 = *(const s16x8*)bp0, w1 = *(const s16x8*)bp1;
#pragma unroll
  for (int k0=0; k0<CD; k0+=32){
    s16x8 na0 = *(const s16x8*)(ap0 + k0+32);
    s16x8 na1 = *(const s16x8*)(ap1 + k0+32);
    s16x8 nw0 = *(const s16x8*)(bp0 + k0+32);
    s16x8 nw1 = *(const s16x8*)(bp1 + k0+32);
    acc[0][0] = MFMA16(a0, w0, acc[0][0]);
    acc[0][1] = MFMA16(a0, w1, acc[0][1]);
    acc[1][0] = MFMA16(a1, w0, acc[1][0]);
    acc[1][1] = MFMA16(a1, w1, acc[1][1]);
    a0=na0; a1=na1; w0=nw0; w1=nw1;
  }
#pragma unroll
  for (int mi=0;mi<2;++mi)
#pragma unroll
    for (int ni=0;ni<2;++ni){
      int c = c0 + ni*16 + ln16;
#pragma unroll
      for (int r=0;r<4;++r){
        int n = m0 + mi*16 + g*4 + r;
        qb[((size_t)bI*NTOK + n)*CD + c] = f2b(acc[mi][ni][r] * SC2);
      }
    }
}

// ---- conv as GEMM over k'=(khw,ci), pipelined, fully unrolled. grid (49,4)
__global__ __launch_bounds__(256) void k_conv(const unsigned short* __restrict__ xbf,
      const unsigned short* __restrict__ srwb2, const float* __restrict__ srb,
      float* __restrict__ convo){
  const int tid=threadIdx.x, wv=tid>>6, l=tid&63, g=l>>4, ln16=l&15;
  const int m0 = blockIdx.x*64 + (wv>>1)*32;
  const int c0 = blockIdx.y*64 + (wv&1)*32;
  size_t abase[2][4];
#pragma unroll
  for (int mi=0;mi<2;++mi){
    int m = m0 + mi*16 + ln16;
    int bb = (m>=2352)?3:(m>=1568)?2:(m>=784)?1:0;
    int nk = m - bb*784;
    int pp = (nk*9363)>>18, qq = nk - pp*28;
#pragma unroll
    for (int khw=0;khw<4;++khw){
      int kh = khw>>1, kw = khw&1;
      abase[mi][khw] = ((size_t)bb*NTOK + (2*pp+kh)*56 + 2*qq+kw)*CD;
    }
  }
  const unsigned short* wp0 = &srwb2[(size_t)(c0+ln16)*1024 + g*8];
  const unsigned short* wp1 = wp0 + 16*1024;
  f32x4 acc[2][2] = {};
  s16x8 a0 = *(const s16x8*)&xbf[abase[0][0] + g*8];
  s16x8 a1 = *(const s16x8*)&xbf[abase[1][0] + g*8];
  s16x8 w0 = *(const s16x8*)wp0;
  s16x8 w1 = *(const s16x8*)wp1;
#pragma unroll
  for (int s=0; s<32; ++s){
    const int s1 = s+1;
    const int khw2 = (s1>>3)&3, kc2 = (s1&7)*32;
    const int woff = (s1&31)*32;
    s16x8 na0 = *(const s16x8*)&xbf[abase[0][khw2] + kc2 + g*8];
    s16x8 na1 = *(const s16x8*)&xbf[abase[1][khw2] + kc2 + g*8];
    s16x8 nw0 = *(const s16x8*)(wp0 + woff);
    s16x8 nw1 = *(const s16x8*)(wp1 + woff);
    acc[0][0] = MFMA16(a0, w0, acc[0][0]);
    acc[0][1] = MFMA16(a0, w1, acc[0][1]);
    acc[1][0] = MFMA16(a1, w0, acc[1][0]);
    acc[1][1] = MFMA16(a1, w1, acc[1][1]);
    a0=na0; a1=na1; w0=nw0; w1=nw1;
  }
#pragma unroll
  for (int mi=0;mi<2;++mi)
#pragma unroll
    for (int ni=0;ni<2;++ni){
      int c = c0 + ni*16 + ln16;
      float bias = srb[c];
#pragma unroll
      for (int r=0;r<4;++r){
        int m = m0 + mi*16 + g*4 + r;
        convo[(size_t)m*CD + c] = acc[mi][ni][r] + bias;
      }
    }
}

// ---- LayerNorm (f32 in, bf16 out). grid 3136, block 256
__global__ void k_ln(const float* __restrict__ co, const float* __restrict__ gam,
                     const float* __restrict__ bet, unsigned short* __restrict__ kvbf){
  const int row = blockIdx.x, t = threadIdx.x;
  float v = co[(size_t)row*CD + t];
  float s = v, s2 = v*v;
#pragma unroll
  for (int o=32; o>0; o>>=1){ s += __shfl_down(s,o); s2 += __shfl_down(s2,o); }
  __shared__ float ps[4], ps2[4];
  int wid = t>>6, lane = t&63;
  if (lane==0){ ps[wid]=s; ps2[wid]=s2; }
  __syncthreads();
  if (t==0){
    float a = ps[0]+ps[1]+ps[2]+ps[3];
    float a2 = ps2[0]+ps2[1]+ps2[2]+ps2[3];
    float mu = a*(1.f/CD);
    float var = a2*(1.f/CD) - mu*mu;
    ps[0] = mu; ps2[0] = rsqrtf(var + 1e-5f);
  }
  __syncthreads();
  float mu = ps[0], rs = ps2[0];
  kvbf[(size_t)row*CD + t] = f2b((v-mu)*rs*gam[t] + bet[t]);
}

// ---- kv projection + scatter: K rows chunk-permuted, V transposed. grid (49,8)
__global__ __launch_bounds__(256) void k_kv(const unsigned short* __restrict__ kvbf,
      const unsigned short* __restrict__ WkvT, unsigned short* __restrict__ kb,
      unsigned short* __restrict__ vT){
  const int tid=threadIdx.x, wv=tid>>6, l=tid&63, g=l>>4, ln16=l&15;
  const int m0 = blockIdx.x*64 + (wv>>1)*32;
  const int c0 = blockIdx.y*64 + (wv&1)*32;
  const unsigned short* ap0 = &kvbf[(size_t)(m0+ln16)*CD + g*8];
  const unsigned short* ap1 = ap0 + 16*CD;
  const unsigned short* bp0 = &WkvT[(size_t)(c0+ln16)*CD + g*8];
  const unsigned short* bp1 = bp0 + 16*CD;
  f32x4 acc[2][2] = {};
  s16x8 a0 = *(const s16x8*)ap0, a1 = *(const s16x8*)ap1;
  s16x8 w0 = *(const s16x8*)bp0, w1 = *(const s16x8*)bp1;
#pragma unroll
  for (int k0=0; k0<CD; k0+=32){
    s16x8 na0 = *(const s16x8*)(ap0 + k0+32);
    s16x8 na1 = *(const s16x8*)(ap1 + k0+32);
    s16x8 nw0 = *(const s16x8*)(bp0 + k0+32);
    s16x8 nw1 = *(const s16x8*)(bp1 + k0+32);
    acc[0][0] = MFMA16(a0, w0, acc[0][0]);
    acc[0][1] = MFMA16(a0, w1, acc[0][1]);
    acc[1][0] = MFMA16(a1, w0, acc[1][0]);
    acc[1][1] = MFMA16(a1, w1, acc[1][1]);
    a0=na0; a1=na1; w0=nw0; w1=nw1;
  }
#pragma unroll
  for (int mi=0;mi<2;++mi)
#pragma unroll
    for (int ni=0;ni<2;++ni){
      int c2 = c0 + ni*16 + ln16;
      int d = c2>>4, hh = (c2>>1)&7;
#pragma unroll
      for (int r=0;r<4;++r){
        int m = m0 + mi*16 + g*4 + r;
        int bq = (m>=2352)?3:(m>=1568)?2:(m>=784)?1:0;
        int nk = m - bq*784;
        unsigned short val = f2b(acc[mi][ni][r]);
        if (c2&1){
          vT[(((size_t)bq*NH+hh)*HD + d)*NKVP + nk] = val;
        } else {
          int chunk = nk & ~31, pos = nk & 31;
          int gg = pos>>3, jj = pos&7;
          int row = (jj<4) ? (gg*4+jj) : (16 + gg*4 + (jj-4));
          kb[(((size_t)bq*NH+hh)*NKVP + chunk + row)*HD + d] = val;
        }
      }
    }
}

// ---- fused attention: LDS double-buffered K/V (global_load_lds), 2-phase pipeline.
// grid (32, 49) = (bh, ntile) -> bh pins to XCD bh%8. 4 waves x 16 q-rows.
__global__ __launch_bounds__(256) void k_attn(const unsigned short* __restrict__ qb,
      const unsigned short* __restrict__ kb, const unsigned short* __restrict__ vT,
      const unsigned short* __restrict__ bias2, unsigned short* __restrict__ aout){
  __shared__ unsigned short kv[2][2048];   // [buf][K:1024 shorts | V:1024 shorts] = 4KB each
  const int tid=threadIdx.x, wv=tid>>6, l=tid&63, g=l>>4, ln16=l&15;
  const int bh = blockIdx.x, b = bh>>3, h = bh&7;
  const int nw = blockIdx.y*64 + wv*16;
  const s16x8 qf = *(const s16x8*)&qb[((size_t)b*NTOK + nw + ln16)*CD + h*HD + g*8];
  const unsigned short* kbase = kb + (size_t)bh*NKVP*HD;
  const unsigned short* vbase = vT + (size_t)bh*HD*NKVP;
  const unsigned short* bp = bias2 + (size_t)(nw + ln16)*NKVP + g*8;
  // per-wave staging source: waves 0-1 stage K (linear), waves 2-3 stage V rows
  const unsigned short* sp = (wv < 2)
      ? (kbase + wv*512 + l*8)
      : (vbase + (size_t)((wv&1)*16 + (l>>2))*NKVP + (l&3)*8);
  const int sstep = (wv < 2) ? 1024 : 32;
  unsigned short* ldst0 = &kv[0][wv*512];
  unsigned short* ldst1 = &kv[1][wv*512];
  f32x4 accO0 = {}, accO1 = {};
  float S = 0.f;
  const f32x4 zf = {};
  // prologue: stage chunk 0 into buf 0
  gload16(sp, ldst0);
  u16x8 bb = *(const u16x8*)bp;
  __syncthreads();
  int cur = 0;
  for (int it=0; it<25; ++it){
    u16x8 nbb = bb;
    if (it < 24){
      gload16(sp + (it+1)*sstep, cur ? ldst0 : ldst1);   // stage next chunk into other buf
      nbb = *(const u16x8*)(bp + (it+1)*32);
    }
    __builtin_amdgcn_sched_barrier(0);                   // pin stage issue before compute
    const unsigned short* kc = kv[cur];
    s16x8 ka0 = *(const s16x8*)&kc[ln16*32 + g*8];
    s16x8 ka1 = *(const s16x8*)&kc[512 + ln16*32 + g*8];
    s16x8 v0  = *(const s16x8*)&kc[1024 + ln16*32 + g*8];
    s16x8 v1  = *(const s16x8*)&kc[1536 + ln16*32 + g*8];
    f32x4 d0 = MFMA16(ka0, qf, zf);
    f32x4 d1 = MFMA16(ka1, qf, zf);
    float p[8];
#pragma unroll
    for (int r=0;r<4;++r){
      p[r]   = exp2f(d0[r] + b2f(bb[r]));
      p[4+r] = exp2f(d1[r] + b2f(bb[4+r]));
    }
    S += ((p[0]+p[1])+(p[2]+p[3])) + ((p[4]+p[5])+(p[6]+p[7]));
    s16x8 pf;
#pragma unroll
    for (int j=0;j<8;++j) pf[j] = (short)f2b_fast(p[j]);
    accO0 = MFMA16(pf, v0, accO0);
    accO1 = MFMA16(pf, v1, accO1);
    __syncthreads();                                     // drain stage, all waves done reading
    cur ^= 1; bb = nbb;
  }
  S += __shfl_xor(S, 16);
  S += __shfl_xor(S, 32);
#pragma unroll
  for (int r=0;r<4;++r){
    float Sr = __shfl(S, g*4 + r);
    float inv = 1.f / Sr;
    int n = nw + g*4 + r;
    aout[((size_t)b*NTOK + n)*CD + h*HD + ln16]      = f2b(accO0[r]*inv);
    aout[((size_t)b*NTOK + n)*CD + h*HD + 16 + ln16] = f2b(accO1[r]*inv);
  }
}

// ---- out projection: A=pwT rows c, B=aout rows n, pipelined. grid (196,4)
__global__ __launch_bounds__(256) void k_proj(const unsigned short* __restrict__ ain,
      const unsigned short* __restrict__ pwT, const float* __restrict__ pb,
      float* __restrict__ out){
  const int tid=threadIdx.x, wv=tid>>6, l=tid&63, g=l>>4, ln16=l&15;
  const int bI = blockIdx.x/49;
  const int n0 = (blockIdx.x%49)*64;
  const int nsub = n0 + (wv&1)*32;
  const int c0 = blockIdx.y*64 + (wv>>1)*32;
  const unsigned short* ap0 = &pwT[(size_t)(c0+ln16)*CD + g*8];
  const unsigned short* ap1 = ap0 + 16*CD;
  const unsigned short* bp0 = &ain[((size_t)bI*NTOK + nsub+ln16)*CD + g*8];
  const unsigned short* bp1 = bp0 + 16*CD;
  f32x4 acc[2][2] = {};   // [mi over c][ni over n]
  s16x8 a0 = *(const s16x8*)ap0, a1 = *(const s16x8*)ap1;
  s16x8 w0 = *(const s16x8*)bp0, w1 = *(const s16x8*)bp1;
#pragma unroll
  for (int k0=0; k0<CD; k0+=32){
    s16x8 na0 = *(const s16x8*)(ap0 + k0+32);
    s16x8 na1 = *(const s16x8*)(ap1 + k0+32);
    s16x8 nw0 = *(const s16x8*)(bp0 + k0+32);
    s16x8 nw1 = *(const s16x8*)(bp1 + k0+32);
    acc[0][0] = MFMA16(a0, w0, acc[0][0]);
    acc[0][1] = MFMA16(a0, w1, acc[0][1]);
    acc[1][0] = MFMA16(a1, w0, acc[1][0]);
    acc[1][1] = MFMA16(a1, w1, acc[1][1]);
    a0=na0; a1=na1; w0=nw0; w1=nw1;
  }
#pragma unroll
  for (int mi=0;mi<2;++mi)
#pragma unroll
    for (int r=0;r<4;++r){
      int c = c0 + mi*16 + g*4 + r;
      float bias = pb[c];
#pragma unroll
      for (int ni=0;ni<2;++ni){
        int n = nsub + ni*16 + ln16;
        out[((size_t)bI*CD + c)*NTOK + n] = acc[mi][ni][r] + bias;
      }
    }
}

extern "C" void kernel_launch(void* const* d_in, const int* in_sizes, int n_in,
                              void* d_out, int out_size, void* d_ws, size_t ws_size,
                              hipStream_t stream){
  const float* x   = (const float*)d_in[0];
  const float* Wq  = (const float*)d_in[1];
  const float* Wkv = (const float*)d_in[2];
  const float* srw = (const float*)d_in[3];
  const float* srb = (const float*)d_in[4];
  const float* lng = (const float*)d_in[5];
  const float* lnb = (const float*)d_in[6];
  const float* pos = (const float*)d_in[7];
  const float* pw  = (const float*)d_in[8];
  const float* pb  = (const float*)d_in[9];
  float* out = (float*)d_out;

  unsigned char* p = (unsigned char*)d_ws;
  unsigned short* WqT   = (unsigned short*)(p + 0);         // 131072 B
  unsigned short* WkvT  = (unsigned short*)(p + 131072);    // 262144 B
  unsigned short* pwT   = (unsigned short*)(p + 393216);    // 131072 B
  unsigned short* srwb2 = (unsigned short*)(p + 524288);    // 524288 B
  unsigned short* bias2 = (unsigned short*)(p + 1048576);   // 5017600 B (bf16)
  unsigned short* xbf   = (unsigned short*)(p + 6066176);   // 6422528 B
  unsigned short* qbuf  = (unsigned short*)(p + 12488704);  // 6422528 B
  float*          convo = (float*)        (p + 18911232);   // 3211264 B
  unsigned short* kvbf  = (unsigned short*)(p + 22122496);  // 1605632 B
  unsigned short* kbuf  = (unsigned short*)(p + 23728128);  // 1638400 B
  unsigned short* vT    = (unsigned short*)(p + 25366528);  // 1638400 B
  unsigned short* aout  = (unsigned short*)(p + 27004928);  // 6422528 B

  k_prep <<<6096, 256, 0, stream>>>(Wq, Wkv, pw, srw, pos, x,
                                    WqT, WkvT, pwT, srwb2, bias2, xbf, kbuf, vT);
  k_qproj<<<dim3(196,4), 256, 0, stream>>>(xbf, WqT, qbuf);
  k_conv <<<dim3(49,4),  256, 0, stream>>>(xbf, srwb2, srb, convo);
  k_ln   <<<3136, 256, 0, stream>>>(convo, lng, lnb, kvbf);
  k_kv   <<<dim3(49,8),  256, 0, stream>>>(kvbf, WkvT, kbuf, vT);
  k_attn <<<dim3(32,49), 256, 0, stream>>>(qbuf, kbuf, vT, bias2, aout);
  k_proj <<<dim3(196,4), 256, 0, stream>>>(aout, pwT, pb, out);
}

// Round 10
// 193.373 us; speedup vs baseline: 1.2917x; 1.0247x over previous
//
#include <hip/hip_runtime.h>
#include <hip/hip_bf16.h>

typedef float f32x4 __attribute__((ext_vector_type(4)));
typedef short s16x8 __attribute__((ext_vector_type(8)));
typedef unsigned short u16x4 __attribute__((ext_vector_type(4)));
typedef unsigned short u16x8 __attribute__((ext_vector_type(8)));

#define MFMA16(a,b,c) __builtin_amdgcn_mfma_f32_16x16x32_bf16(a,b,c,0,0,0)

#define NTOK 3136
#define NKV  784
#define NKVP 800
#define CD   256
#define NH   8
#define HD   32
#define PEW  111
#define LOG2E 1.4426950408889634f
#define SC2  (0.17677669529663687f * 1.4426950408889634f)

static __device__ __forceinline__ unsigned short f2b(float f){
  unsigned int u = __float_as_uint(f);
  return (unsigned short)((u + 0x7fffu + ((u>>16)&1u)) >> 16);
}
static __device__ __forceinline__ unsigned short f2b_fast(float f){
  __hip_bfloat16 h = __float2bfloat16(f);
  return *reinterpret_cast<unsigned short*>(&h);
}
static __device__ __forceinline__ float b2f(unsigned short u){
  return __uint_as_float(((unsigned int)u)<<16);
}
static __device__ __forceinline__ void gload16(const unsigned short* g, unsigned short* l){
  __builtin_amdgcn_global_load_lds(
      (const __attribute__((address_space(1))) unsigned int*)g,
      (__attribute__((address_space(3))) unsigned int*)l, 16, 0, 0);
}

// ---- fused prep: [0,2048) prepw | [2048,2176) pad | [2176,5312) bias | [5312,6096) xt
__global__ __launch_bounds__(256) void k_prep(
      const float* __restrict__ Wq, const float* __restrict__ Wkv,
      const float* __restrict__ pw, const float* __restrict__ srw,
      const float* __restrict__ pos, const float* __restrict__ x,
      unsigned short* __restrict__ WqT, unsigned short* __restrict__ WkvT,
      unsigned short* __restrict__ pwT, unsigned short* __restrict__ srwb2,
      unsigned short* __restrict__ bias2, unsigned short* __restrict__ xbf,
      unsigned short* __restrict__ kb, unsigned short* __restrict__ vT){
  __shared__ float tile[64][65];
  const int blk = blockIdx.x, t = threadIdx.x;
  if (blk < 2048){
    int i = blk*256 + t;
    if (i < 65536){ int nn=i>>8, kk=i&255; WqT[i] = f2b(Wq[kk*256+nn]); }
    else if (i < 196608){ int j=i-65536; int c2=j>>8, kk=j&255; WkvT[j] = f2b(Wkv[kk*512+c2]); }
    else if (i < 262144){ int j=i-196608; int cc=j>>8, kk=j&255; pwT[j] = f2b(pw[kk*256+cc]); }
    else { int j=i-262144; int o=j>>10, rem=j&1023, khw=rem>>8, ci=rem&255;
           srwb2[j] = f2b(srw[o*1024 + ci*4 + khw]); }
  } else if (blk < 2176){
    int i = (blk-2048)*256 + t;                 // 32768
    if (i < 16384){
      int bh=i>>9, r=i&511, ridx=r>>5, d=r&31;
      int row = 776 + (ridx&7) + (ridx>>3)*16;  // permuted pad rows
      kb[((size_t)bh*NKVP + row)*HD + d] = 0;
    } else {
      int j=i-16384;
      int bh=j>>9, r=j&511, d=r>>4, key=784+(r&15);
      vT[((size_t)bh*HD + d)*NKVP + key] = 0;
    }
  } else if (blk < 5312){
    int n = blk - 2176;
    if (t < 200){
      int nr = (n*9363)>>19, nc = n - nr*56;
      u16x4 o;
#pragma unroll
      for (int j=0;j<4;++j){
        int key = t*4 + j;
        float v;
        if (key < NKV){
          int tt = (key*9363)>>19, mm = key - tt*56;
          v = pos[(tt-nr+55)*PEW + (mm-nc+55)] * LOG2E;
        } else v = -100000.f;
        o[j] = f2b(v);
      }
      *(u16x4*)&bias2[(size_t)n*NKVP + t*4] = o;
    }
  } else {
    int bx = blk - 5312;
    const int n0 = (bx%49)*64; int c4 = bx/49;
    const int c0 = (c4&3)*64, b = c4>>2;
    const int tx = t&15, ty = t>>4;
#pragma unroll
    for (int j=0;j<4;++j){
      f32x4 v = *(const f32x4*)&x[(size_t)(b*CD + c0+ty+j*16)*NTOK + n0 + tx*4];
      tile[ty+j*16][tx*4+0]=v[0]; tile[ty+j*16][tx*4+1]=v[1];
      tile[ty+j*16][tx*4+2]=v[2]; tile[ty+j*16][tx*4+3]=v[3];
    }
    __syncthreads();
    const int nr = t>>2, ccb = (t&3)*16;
    u16x8 o0, o1;
#pragma unroll
    for (int u=0;u<8;++u){ o0[u] = f2b(tile[ccb+u][nr]); o1[u] = f2b(tile[ccb+8+u][nr]); }
    unsigned short* dst = &xbf[((size_t)b*NTOK + n0+nr)*CD + c0 + ccb];
    *(u16x8*)dst = o0;
    *(u16x8*)(dst+8) = o1;
  }
}

// ---- q projection (pre-scaled by scale*log2e), pipelined. grid (196,4)
__global__ __launch_bounds__(256) void k_qproj(const unsigned short* __restrict__ xbf,
      const unsigned short* __restrict__ WqT, unsigned short* __restrict__ qb){
  const int tid=threadIdx.x, wv=tid>>6, l=tid&63, g=l>>4, ln16=l&15;
  const int bI = blockIdx.x/49;
  const int n0 = (blockIdx.x%49)*64;
  const int m0 = n0 + (wv>>1)*32;
  const int c0 = blockIdx.y*64 + (wv&1)*32;
  const unsigned short* ap0 = &xbf[((size_t)bI*NTOK + m0+ln16)*CD + g*8];
  const unsigned short* ap1 = ap0 + 16*CD;
  const unsigned short* bp0 = &WqT[(size_t)(c0+ln16)*CD + g*8];
  const unsigned short* bp1 = bp0 + 16*CD;
  f32x4 acc[2][2] = {};
  s16x8 a0 = *(const s16x8*)ap0, a1 = *(const s16x8*)ap1;
  s16x8 w0 = *(const s16x8*)bp0, w1 = *(const s16x8*)bp1;
#pragma unroll
  for (int k0=0; k0<CD; k0+=32){
    s16x8 na0 = *(const s16x8*)(ap0 + k0+32);
    s16x8 na1 = *(const s16x8*)(ap1 + k0+32);
    s16x8 nw0 = *(const s16x8*)(bp0 + k0+32);
    s16x8 nw1 = *(const s16x8*)(bp1 + k0+32);
    acc[0][0] = MFMA16(a0, w0, acc[0][0]);
    acc[0][1] = MFMA16(a0, w1, acc[0][1]);
    acc[1][0] = MFMA16(a1, w0, acc[1][0]);
    acc[1][1] = MFMA16(a1, w1, acc[1][1]);
    a0=na0; a1=na1; w0=nw0; w1=nw1;
  }
#pragma unroll
  for (int mi=0;mi<2;++mi)
#pragma unroll
    for (int ni=0;ni<2;++ni){
      int c = c0 + ni*16 + ln16;
#pragma unroll
      for (int r=0;r<4;++r){
        int n = m0 + mi*16 + g*4 + r;
        qb[((size_t)bI*NTOK + n)*CD + c] = f2b(acc[mi][ni][r] * SC2);
      }
    }
}

// ---- conv as GEMM over k'=(khw,ci), pipelined, fully unrolled. grid (49,4)
__global__ __launch_bounds__(256) void k_conv(const unsigned short* __restrict__ xbf,
      const unsigned short* __restrict__ srwb2, const float* __restrict__ srb,
      float* __restrict__ convo){
  const int tid=threadIdx.x, wv=tid>>6, l=tid&63, g=l>>4, ln16=l&15;
  const int m0 = blockIdx.x*64 + (wv>>1)*32;
  const int c0 = blockIdx.y*64 + (wv&1)*32;
  size_t abase[2][4];
#pragma unroll
  for (int mi=0;mi<2;++mi){
    int m = m0 + mi*16 + ln16;
    int bb = (m>=2352)?3:(m>=1568)?2:(m>=784)?1:0;
    int nk = m - bb*784;
    int pp = (nk*9363)>>18, qq = nk - pp*28;
#pragma unroll
    for (int khw=0;khw<4;++khw){
      int kh = khw>>1, kw = khw&1;
      abase[mi][khw] = ((size_t)bb*NTOK + (2*pp+kh)*56 + 2*qq+kw)*CD;
    }
  }
  const unsigned short* wp0 = &srwb2[(size_t)(c0+ln16)*1024 + g*8];
  const unsigned short* wp1 = wp0 + 16*1024;
  f32x4 acc[2][2] = {};
  s16x8 a0 = *(const s16x8*)&xbf[abase[0][0] + g*8];
  s16x8 a1 = *(const s16x8*)&xbf[abase[1][0] + g*8];
  s16x8 w0 = *(const s16x8*)wp0;
  s16x8 w1 = *(const s16x8*)wp1;
#pragma unroll
  for (int s=0; s<32; ++s){
    const int s1 = s+1;
    const int khw2 = (s1>>3)&3, kc2 = (s1&7)*32;
    const int woff = (s1&31)*32;
    s16x8 na0 = *(const s16x8*)&xbf[abase[0][khw2] + kc2 + g*8];
    s16x8 na1 = *(const s16x8*)&xbf[abase[1][khw2] + kc2 + g*8];
    s16x8 nw0 = *(const s16x8*)(wp0 + woff);
    s16x8 nw1 = *(const s16x8*)(wp1 + woff);
    acc[0][0] = MFMA16(a0, w0, acc[0][0]);
    acc[0][1] = MFMA16(a0, w1, acc[0][1]);
    acc[1][0] = MFMA16(a1, w0, acc[1][0]);
    acc[1][1] = MFMA16(a1, w1, acc[1][1]);
    a0=na0; a1=na1; w0=nw0; w1=nw1;
  }
#pragma unroll
  for (int mi=0;mi<2;++mi)
#pragma unroll
    for (int ni=0;ni<2;++ni){
      int c = c0 + ni*16 + ln16;
      float bias = srb[c];
#pragma unroll
      for (int r=0;r<4;++r){
        int m = m0 + mi*16 + g*4 + r;
        convo[(size_t)m*CD + c] = acc[mi][ni][r] + bias;
      }
    }
}

// ---- LayerNorm (f32 in, bf16 out). grid 3136, block 256
__global__ void k_ln(const float* __restrict__ co, const float* __restrict__ gam,
                     const float* __restrict__ bet, unsigned short* __restrict__ kvbf){
  const int row = blockIdx.x, t = threadIdx.x;
  float v = co[(size_t)row*CD + t];
  float s = v, s2 = v*v;
#pragma unroll
  for (int o=32; o>0; o>>=1){ s += __shfl_down(s,o); s2 += __shfl_down(s2,o); }
  __shared__ float ps[4], ps2[4];
  int wid = t>>6, lane = t&63;
  if (lane==0){ ps[wid]=s; ps2[wid]=s2; }
  __syncthreads();
  if (t==0){
    float a = ps[0]+ps[1]+ps[2]+ps[3];
    float a2 = ps2[0]+ps2[1]+ps2[2]+ps2[3];
    float mu = a*(1.f/CD);
    float var = a2*(1.f/CD) - mu*mu;
    ps[0] = mu; ps2[0] = rsqrtf(var + 1e-5f);
  }
  __syncthreads();
  float mu = ps[0], rs = ps2[0];
  kvbf[(size_t)row*CD + t] = f2b((v-mu)*rs*gam[t] + bet[t]);
}

// ---- kv projection + scatter: K rows chunk-permuted, V transposed. grid (49,8)
__global__ __launch_bounds__(256) void k_kv(const unsigned short* __restrict__ kvbf,
      const unsigned short* __restrict__ WkvT, unsigned short* __restrict__ kb,
      unsigned short* __restrict__ vT){
  const int tid=threadIdx.x, wv=tid>>6, l=tid&63, g=l>>4, ln16=l&15;
  const int m0 = blockIdx.x*64 + (wv>>1)*32;
  const int c0 = blockIdx.y*64 + (wv&1)*32;
  const unsigned short* ap0 = &kvbf[(size_t)(m0+ln16)*CD + g*8];
  const unsigned short* ap1 = ap0 + 16*CD;
  const unsigned short* bp0 = &WkvT[(size_t)(c0+ln16)*CD + g*8];
  const unsigned short* bp1 = bp0 + 16*CD;
  f32x4 acc[2][2] = {};
  s16x8 a0 = *(const s16x8*)ap0, a1 = *(const s16x8*)ap1;
  s16x8 w0 = *(const s16x8*)bp0, w1 = *(const s16x8*)bp1;
#pragma unroll
  for (int k0=0; k0<CD; k0+=32){
    s16x8 na0 = *(const s16x8*)(ap0 + k0+32);
    s16x8 na1 = *(const s16x8*)(ap1 + k0+32);
    s16x8 nw0 = *(const s16x8*)(bp0 + k0+32);
    s16x8 nw1 = *(const s16x8*)(bp1 + k0+32);
    acc[0][0] = MFMA16(a0, w0, acc[0][0]);
    acc[0][1] = MFMA16(a0, w1, acc[0][1]);
    acc[1][0] = MFMA16(a1, w0, acc[1][0]);
    acc[1][1] = MFMA16(a1, w1, acc[1][1]);
    a0=na0; a1=na1; w0=nw0; w1=nw1;
  }
#pragma unroll
  for (int mi=0;mi<2;++mi)
#pragma unroll
    for (int ni=0;ni<2;++ni){
      int c2 = c0 + ni*16 + ln16;
      int d = c2>>4, hh = (c2>>1)&7;
#pragma unroll
      for (int r=0;r<4;++r){
        int m = m0 + mi*16 + g*4 + r;
        int bq = (m>=2352)?3:(m>=1568)?2:(m>=784)?1:0;
        int nk = m - bq*784;
        unsigned short val = f2b(acc[mi][ni][r]);
        if (c2&1){
          vT[(((size_t)bq*NH+hh)*HD + d)*NKVP + nk] = val;
        } else {
          int chunk = nk & ~31, pos = nk & 31;
          int gg = pos>>3, jj = pos&7;
          int row = (jj<4) ? (gg*4+jj) : (16 + gg*4 + (jj-4));
          kb[(((size_t)bq*NH+hh)*NKVP + chunk + row)*HD + d] = val;
        }
      }
    }
}

// ---- fused attention: 3-buffer LDS pipeline, counted vmcnt, swizzled slots.
// grid (32, 49) = (bh, ntile) -> bh pins to XCD bh%8. 4 waves x 16 q-rows.
__global__ __launch_bounds__(256) void k_attn(const unsigned short* __restrict__ qb,
      const unsigned short* __restrict__ kb, const unsigned short* __restrict__ vT,
      const unsigned short* __restrict__ bias2, unsigned short* __restrict__ aout){
  __shared__ unsigned short kv0[2048], kv1[2048], kv2[2048];  // K:1024 | V:1024 shorts
  const int tid=threadIdx.x, wv=tid>>6, l=tid&63, g=l>>4, ln16=l&15;
  const int bh = blockIdx.x, b = bh>>3, h = bh&7;
  const int nw = blockIdx.y*64 + wv*16;
  const s16x8 qf = *(const s16x8*)&qb[((size_t)b*NTOK + nw + ln16)*CD + h*HD + g*8];
  const unsigned short* kbase = kb + (size_t)bh*NKVP*HD;
  const unsigned short* vbase = vT + (size_t)bh*HD*NKVP;
  const unsigned short* bp = bias2 + (size_t)(nw + ln16)*NKVP + g*8;
  // staging: slot swizzle on global source (write side)
  const int lslot = ((l&3)^((l>>3)&3))*8;
  const unsigned short* sp = (wv < 2)
      ? (kbase + (size_t)(wv*16 + (l>>2))*HD + lslot)
      : (vbase + (size_t)((wv-2)*16 + (l>>2))*NKVP + lslot);
  const int sstep = (wv < 2) ? 1024 : 32;
  // swizzled LDS read offset (read side, same involution)
  const int ko0 = ln16*32 + (g ^ ((ln16>>1)&3))*8;
  unsigned short *bA = kv0, *bB = kv1, *bC = kv2;
  f32x4 accO0 = {}, accO1 = {};
  float S = 0.f;
  const f32x4 zf = {};
  // prologue: stage chunks 0,1; bias 0,1
  gload16(sp,          bA + wv*512);
  u16x8 bb = *(const u16x8*)bp;
  gload16(sp + sstep,  bB + wv*512);
  u16x8 b1 = *(const u16x8*)(bp + 32);
  for (int it=0; it<25; ++it){
    if (it < 23) asm volatile("s_waitcnt vmcnt(2)" ::: "memory");
    else         asm volatile("s_waitcnt vmcnt(0)" ::: "memory");
    __builtin_amdgcn_s_barrier();
    __builtin_amdgcn_sched_barrier(0);
    u16x8 b2 = b1;
    if (it < 23){
      gload16(sp + (it+2)*sstep, bC + wv*512);   // bC == buf read at it-1, all waves past it
      b2 = *(const u16x8*)(bp + (it+2)*32);
    }
    // compute chunk it from bA
    s16x8 ka0 = *(const s16x8*)&bA[ko0];
    s16x8 ka1 = *(const s16x8*)&bA[512 + ko0];
    s16x8 v0  = *(const s16x8*)&bA[1024 + ko0];
    s16x8 v1  = *(const s16x8*)&bA[1536 + ko0];
    __builtin_amdgcn_s_setprio(1);
    f32x4 d0 = MFMA16(ka0, qf, zf);
    f32x4 d1 = MFMA16(ka1, qf, zf);
    float p[8];
#pragma unroll
    for (int r=0;r<4;++r){
      p[r]   = exp2f(d0[r] + b2f(bb[r]));
      p[4+r] = exp2f(d1[r] + b2f(bb[4+r]));
    }
    S += ((p[0]+p[1])+(p[2]+p[3])) + ((p[4]+p[5])+(p[6]+p[7]));
    s16x8 pf;
#pragma unroll
    for (int j=0;j<8;++j) pf[j] = (short)f2b_fast(p[j]);
    accO0 = MFMA16(pf, v0, accO0);
    accO1 = MFMA16(pf, v1, accO1);
    __builtin_amdgcn_s_setprio(0);
    // rotate buffers and bias regs
    unsigned short* tmp = bA; bA = bB; bB = bC; bC = tmp;
    bb = b1; b1 = b2;
  }
  S += __shfl_xor(S, 16);
  S += __shfl_xor(S, 32);
#pragma unroll
  for (int r=0;r<4;++r){
    float Sr = __shfl(S, g*4 + r);
    float inv = 1.f / Sr;
    int n = nw + g*4 + r;
    aout[((size_t)b*NTOK + n)*CD + h*HD + ln16]      = f2b(accO0[r]*inv);
    aout[((size_t)b*NTOK + n)*CD + h*HD + 16 + ln16] = f2b(accO1[r]*inv);
  }
}

// ---- out projection: A=pwT rows c, B=aout rows n, pipelined. grid (196,4)
__global__ __launch_bounds__(256) void k_proj(const unsigned short* __restrict__ ain,
      const unsigned short* __restrict__ pwT, const float* __restrict__ pb,
      float* __restrict__ out){
  const int tid=threadIdx.x, wv=tid>>6, l=tid&63, g=l>>4, ln16=l&15;
  const int bI = blockIdx.x/49;
  const int n0 = (blockIdx.x%49)*64;
  const int nsub = n0 + (wv&1)*32;
  const int c0 = blockIdx.y*64 + (wv>>1)*32;
  const unsigned short* ap0 = &pwT[(size_t)(c0+ln16)*CD + g*8];
  const unsigned short* ap1 = ap0 + 16*CD;
  const unsigned short* bp0 = &ain[((size_t)bI*NTOK + nsub+ln16)*CD + g*8];
  const unsigned short* bp1 = bp0 + 16*CD;
  f32x4 acc[2][2] = {};   // [mi over c][ni over n]
  s16x8 a0 = *(const s16x8*)ap0, a1 = *(const s16x8*)ap1;
  s16x8 w0 = *(const s16x8*)bp0, w1 = *(const s16x8*)bp1;
#pragma unroll
  for (int k0=0; k0<CD; k0+=32){
    s16x8 na0 = *(const s16x8*)(ap0 + k0+32);
    s16x8 na1 = *(const s16x8*)(ap1 + k0+32);
    s16x8 nw0 = *(const s16x8*)(bp0 + k0+32);
    s16x8 nw1 = *(const s16x8*)(bp1 + k0+32);
    acc[0][0] = MFMA16(a0, w0, acc[0][0]);
    acc[0][1] = MFMA16(a0, w1, acc[0][1]);
    acc[1][0] = MFMA16(a1, w0, acc[1][0]);
    acc[1][1] = MFMA16(a1, w1, acc[1][1]);
    a0=na0; a1=na1; w0=nw0; w1=nw1;
  }
#pragma unroll
  for (int mi=0;mi<2;++mi)
#pragma unroll
    for (int r=0;r<4;++r){
      int c = c0 + mi*16 + g*4 + r;
      float bias = pb[c];
#pragma unroll
      for (int ni=0;ni<2;++ni){
        int n = nsub + ni*16 + ln16;
        out[((size_t)bI*CD + c)*NTOK + n] = acc[mi][ni][r] + bias;
      }
    }
}

extern "C" void kernel_launch(void* const* d_in, const int* in_sizes, int n_in,
                              void* d_out, int out_size, void* d_ws, size_t ws_size,
                              hipStream_t stream){
  const float* x   = (const float*)d_in[0];
  const float* Wq  = (const float*)d_in[1];
  const float* Wkv = (const float*)d_in[2];
  const float* srw = (const float*)d_in[3];
  const float* srb = (const float*)d_in[4];
  const float* lng = (const float*)d_in[5];
  const float* lnb = (const float*)d_in[6];
  const float* pos = (const float*)d_in[7];
  const float* pw  = (const float*)d_in[8];
  const float* pb  = (const float*)d_in[9];
  float* out = (float*)d_out;

  unsigned char* p = (unsigned char*)d_ws;
  unsigned short* WqT   = (unsigned short*)(p + 0);         // 131072 B
  unsigned short* WkvT  = (unsigned short*)(p + 131072);    // 262144 B
  unsigned short* pwT   = (unsigned short*)(p + 393216);    // 131072 B
  unsigned short* srwb2 = (unsigned short*)(p + 524288);    // 524288 B
  unsigned short* bias2 = (unsigned short*)(p + 1048576);   // 5017600 B (bf16)
  unsigned short* xbf   = (unsigned short*)(p + 6066176);   // 6422528 B
  unsigned short* qbuf  = (unsigned short*)(p + 12488704);  // 6422528 B
  float*          convo = (float*)        (p + 18911232);   // 3211264 B
  unsigned short* kvbf  = (unsigned short*)(p + 22122496);  // 1605632 B
  unsigned short* kbuf  = (unsigned short*)(p + 23728128);  // 1638400 B
  unsigned short* vT    = (unsigned short*)(p + 25366528);  // 1638400 B
  unsigned short* aout  = (unsigned short*)(p + 27004928);  // 6422528 B

  k_prep <<<6096, 256, 0, stream>>>(Wq, Wkv, pw, srw, pos, x,
                                    WqT, WkvT, pwT, srwb2, bias2, xbf, kbuf, vT);
  k_qproj<<<dim3(196,4), 256, 0, stream>>>(xbf, WqT, qbuf);
  k_conv <<<dim3(49,4),  256, 0, stream>>>(xbf, srwb2, srb, convo);
  k_ln   <<<3136, 256, 0, stream>>>(convo, lng, lnb, kvbf);
  k_kv   <<<dim3(49,8),  256, 0, stream>>>(kvbf, WkvT, kbuf, vT);
  k_attn <<<dim3(32,49), 256, 0, stream>>>(qbuf, kbuf, vT, bias2, aout);
  k_proj <<<dim3(196,4), 256, 0, stream>>>(aout, pwT, pb, out);
}